// Round 9
// baseline (112.485 us; speedup 1.0000x reference)
//
#include <hip/hip_runtime.h>
#include <cstdint>

#define NB   32
#define CIN  128
#define HH   56
#define WW   56
#define KOUT 256
#define HWS  (HH*WW)            // 3136
#define NHW  (NB*HWS)           // 100352
#define PADH 58                 // rows -1..56 -> 0..57 (0 and 57 zero pad)
#define XCNT ((float)(NB*CIN*HWS))
#define WCNT ((float)(KOUT*CIN*9))

// Zero sums + zero the 2 pad rows per image (3584 uint4). Grid 14 x 256.
__global__ __launch_bounds__(256) void init_kernel(uint4* __restrict__ xpad,
                                                   float* __restrict__ sums) {
    int idx = blockIdx.x * 256 + threadIdx.x;        // 0..3583
    if (idx < 2) sums[idx] = 0.0f;
    int n = idx / 112, rem = idx - n * 112;
    int prow = (rem < 56) ? 0 : 57;
    int w = rem % 56;
    xpad[(n * PADH + prow) * WW + w] = make_uint4(0, 0, 0, 0);
}

__device__ __forceinline__ void block_reduce_add(float v, float* dst) {
    #pragma unroll
    for (int off = 32; off > 0; off >>= 1) v += __shfl_down(v, off);
    __shared__ float ws4[4];
    int lane = threadIdx.x & 63, wid = threadIdx.x >> 6;
    if (lane == 0) ws4[wid] = v;
    __syncthreads();
    if (threadIdx.x == 0) {
        float s = ws4[0];
        int nw = (blockDim.x + 63) >> 6;
        for (int i = 1; i < nw; i++) s += ws4[i];
        atomicAdd(dst, s);
    }
}

// Thread per (spatial idx, 32-channel word j); writes into PADDED layout.
__global__ __launch_bounds__(256) void pack_x_kernel(const float* __restrict__ x,
                                                     uint32_t* __restrict__ xpadw,
                                                     float* __restrict__ sums) {
    int j   = blockIdx.x / (NHW / 256);              // 0..3, uniform per block
    int idx = (blockIdx.x - j * (NHW / 256)) * 256 + threadIdx.x;
    int n  = idx / HWS;
    int hw = idx - n * HWS;
    int h  = hw / WW;
    int w  = hw - h * WW;
    const float* p = x + (size_t)n * CIN * HWS + (size_t)(j * 32) * HWS + hw;
    float asum = 0.0f;
    uint32_t bits = 0;
    #pragma unroll
    for (int t = 0; t < 32; t++) {
        float v = p[(size_t)t * HWS];
        asum += fabsf(v);
        bits |= (v > 0.0f ? 1u : 0u) << t;
    }
    xpadw[(((n * PADH + h + 1) * WW + w) << 2) + j] = bits;
    block_reduce_add(asum, &sums[0]);
}

// Thread per (k, tap, word j): block = (tap, j) [36 blocks], lane = k (256).
__global__ __launch_bounds__(256) void pack_w_kernel(const float* __restrict__ wgt,
                                                     uint32_t* __restrict__ wpackTw,
                                                     float* __restrict__ sums) {
    int k   = threadIdx.x;
    int tap = blockIdx.x >> 2;
    int j   = blockIdx.x & 3;
    const float* p = wgt + (size_t)k * CIN * 9 + (size_t)(j * 32) * 9 + tap;
    float asum = 0.0f;
    uint32_t bits = 0;
    #pragma unroll
    for (int t = 0; t < 32; t++) {
        float v = p[(size_t)t * 9];
        asum += fabsf(v);
        bits |= (v > 0.0f ? 1u : 0u) << t;
    }
    wpackTw[(tap * KOUT + k) * 4 + j] = bits;
    block_reduce_add(asum, &sums[1]);
}

// Block = (n,h), 256 threads = 4 kg-waves. ROLLED column-major loop:
// 27 iterations x 2 columns (~1.3 KB hot code — L1I resident, vs ~20 KB
// unrolled in R1..R8 which all converged at 76-78 us). x window staged in
// LDS (one coalesced 168-thread load); inner loads are broadcast
// ds_read_b128 with ~144 cyc of popcount cover. Accumulator SHIFT
// (a0=a1;a1=a2;a2=0) makes every body identical; sb index is runtime (LDS).
__global__ __launch_bounds__(256, 4) void conv_kernel(const uint4* __restrict__ xpad,
                                                      const uint4* __restrict__ wpackT,
                                                      const float* __restrict__ sums,
                                                      const float* __restrict__ bias,
                                                      float* __restrict__ out) {
    __shared__ uint4 xt[168];           // [row][col] = 3 x 56, linear
    __shared__ float sbuf[256 * 10];

    int tid = threadIdx.x;
    int l   = tid & 63, kg = tid >> 6;
    int n   = blockIdx.x / HH, h = blockIdx.x - n * HH;

    uint4 wq[9];
    #pragma unroll
    for (int t = 0; t < 9; t++) wq[t] = wpackT[t * KOUT + tid];

    // stage 3 padded rows (contiguous in xpad): one coalesced load
    const uint4* R0 = xpad + (size_t)(n * PADH + h) * WW;
    if (tid < 168) xt[tid] = R0[tid];

    float scale = (sums[0] * (1.0f / XCNT)) * (sums[1] * (1.0f / WCNT));
    float m2s   = -2.0f * scale;
    float cbase = 1152.0f * scale + bias[tid];

    int pw[9];
    #pragma unroll
    for (int t = 0; t < 9; t++)
        pw[t] = __popc(wq[t].x) + __popc(wq[t].y) + __popc(wq[t].z) + __popc(wq[t].w);
    int cs0 = pw[0] + pw[3] + pw[6];
    int cs2 = pw[2] + pw[5] + pw[8];
    int rterm = 0, cc0 = 0, cc2 = 0;
    if (h == 0)        { rterm = 2*(pw[0]+pw[1]+pw[2]) - 384; cc0 = 128 - 2*pw[0]; cc2 = 128 - 2*pw[2]; }
    else if (h == HH-1){ rterm = 2*(pw[6]+pw[7]+pw[8]) - 384; cc0 = 128 - 2*pw[6]; cc2 = 128 - 2*pw[8]; }
    float KC  = cbase + scale * (float)rterm;                // interior const
    float F0  = KC + scale * (float)(2*cs0 - 384 + cc0);     // w = 0
    float F55 = KC + scale * (float)(2*cs2 - 384 + cc2);     // w = 55

    float* sb    = &sbuf[tid * 10];
    int    fbase = (kg * 64 + (l >> 2)) * 10 + (l & 3) * 2;
    float* o0 = out + ((size_t)(n * KOUT + kg * 64 + (l >> 2)) * HWS + h * WW + (l & 3) * 2);
    float* o1 = o0 + (size_t)16 * HWS;
    float* o2 = o1 + (size_t)16 * HWS;
    float* o3 = o2 + (size_t)16 * HWS;

    __syncthreads();

#define T4(a, q, wt) a += __popc((q).x^(wt).x) + __popc((q).y^(wt).y) + __popc((q).z^(wt).z) + __popc((q).w^(wt).w);
#define FLUSH { \
    *(float2*)(o0) = *(float2*)&sbuf[fbase];       \
    *(float2*)(o1) = *(float2*)&sbuf[fbase + 160]; \
    *(float2*)(o2) = *(float2*)&sbuf[fbase + 320]; \
    *(float2*)(o3) = *(float2*)&sbuf[fbase + 480]; \
    o0 += 8; o1 += 8; o2 += 8; o3 += 8; }

    uint4 qa0, qa1, qa2, qb0, qb1, qb2;
    int a0, a1, a2;

    // prologue: col 0 -> A (consume), col 1 -> B
    qa0 = xt[0]; qa1 = xt[56]; qa2 = xt[112];
    qb0 = xt[1]; qb1 = xt[57]; qb2 = xt[113];
    a0 = cs0; a1 = 0; a2 = 0;            // a0 = out0 (pad col folded), a1 = out1
    T4(a0, qa0, wq[1]) T4(a0, qa1, wq[4]) T4(a0, qa2, wq[7])
    T4(a1, qa0, wq[0]) T4(a1, qa1, wq[3]) T4(a1, qa2, wq[6])

    float KA = F0;                       // first body1 emit (out0) uses F0

    // main loop: i-th iter consumes cols 1+2i (B) and 2+2i (A), emits outs 2i, 2i+1
    #pragma unroll 1
    for (int i = 0; i < 27; ++i) {
        int c = 1 + 2 * i;
        // body1: load col c+1 -> A; consume B (col c); emit out[c-1]
        qa0 = xt[c + 1]; qa1 = xt[c + 57]; qa2 = xt[c + 113];
        T4(a0, qb0, wq[2]) T4(a0, qb1, wq[5]) T4(a0, qb2, wq[8])
        T4(a1, qb0, wq[1]) T4(a1, qb1, wq[4]) T4(a1, qb2, wq[7])
        T4(a2, qb0, wq[0]) T4(a2, qb1, wq[3]) T4(a2, qb2, wq[6])
        sb[(c - 1) & 7] = fmaf(m2s, (float)a0, KA);
        KA = KC;
        a0 = a1; a1 = a2; a2 = 0;
        // body2: load col c+2 -> B (max 55, in range); consume A (col c+1); emit out[c]
        qb0 = xt[c + 2]; qb1 = xt[c + 58]; qb2 = xt[c + 114];
        T4(a0, qa0, wq[2]) T4(a0, qa1, wq[5]) T4(a0, qa2, wq[8])
        T4(a1, qa0, wq[1]) T4(a1, qa1, wq[4]) T4(a1, qa2, wq[7])
        T4(a2, qa0, wq[0]) T4(a2, qa1, wq[3]) T4(a2, qa2, wq[6])
        sb[c & 7] = fmaf(m2s, (float)a0, KC);
        a0 = a1; a1 = a2; a2 = 0;
        if ((i & 3) == 3) FLUSH          // i=3,7,11,15,19,23: outs 8m..8m+7
    }

    // epilogue: consume col 55 (B); emit out54 (a0) and out55 (a1 + pad col cs2)
    T4(a0, qb0, wq[2]) T4(a0, qb1, wq[5]) T4(a0, qb2, wq[8])
    T4(a1, qb0, wq[1]) T4(a1, qb1, wq[4]) T4(a1, qb2, wq[7])
    sb[6] = fmaf(m2s, (float)a0, KC);
    sb[7] = fmaf(m2s, (float)(a1 + cs2), F55);
    FLUSH
}

extern "C" void kernel_launch(void* const* d_in, const int* in_sizes, int n_in,
                              void* d_out, int out_size, void* d_ws, size_t ws_size,
                              hipStream_t stream) {
    const float* x    = (const float*)d_in[0];
    const float* wgt  = (const float*)d_in[1];
    const float* bias = (const float*)d_in[2];
    float* out = (float*)d_out;

    // ws: sums (256B) | xpad 32*58*56 uint4 (1.59MB) | wpackT 2304 uint4 (36KB)
    float* sums   = (float*)d_ws;
    uint4* xpad   = (uint4*)((char*)d_ws + 256);
    uint4* wpackT = (uint4*)((char*)d_ws + 256 + (size_t)NB * PADH * WW * 16);

    hipLaunchKernelGGL(init_kernel, dim3(14), dim3(256), 0, stream, xpad, sums);
    hipLaunchKernelGGL(pack_w_kernel, dim3(36), dim3(256), 0, stream, wgt, (uint32_t*)wpackT, sums);
    hipLaunchKernelGGL(pack_x_kernel, dim3(4 * NHW / 256), dim3(256), 0, stream, x, (uint32_t*)xpad, sums);
    hipLaunchKernelGGL(conv_kernel, dim3(NB * HH), dim3(256), 0, stream, xpad, wpackT, sums, bias, out);
}